// Round 5
// baseline (70.603 us; speedup 1.0000x reference)
//
#include <hip/hip_runtime.h>
#include <math.h>

// SubsetOperator (Gumbel top-K relaxation), B=4096 rows, N=8192 cols, K=8, TAU=1.
// Exp-domain transform: w = exp(s+g-M0); per iter: oh=w/sum; kh+=oh; w*=(1-oh).
// Round-5: persistent blocks process RPB=2 rows; next row's loads are issued
// before the current row's K-loop (which has zero VMEM ops), hiding HBM latency.
// K-loop uses f32x2 packed math (v_pk_fma_f32) + 4-way partial sums.

#define BROWS 4096
#define NCOLS 8192
#define KITER 8
#define THREADS 256
#define RPB 2
#define GRID (BROWS / RPB)        // 2048
#define VECS 8                    // 8 x float4 = 32 elems/thread/row
#define NWAVES (THREADS / 64)     // 4
#define M0 24.0f

typedef float f32x4 __attribute__((ext_vector_type(4)));
typedef float f32x2 __attribute__((ext_vector_type(2)));

__global__ __launch_bounds__(THREADS)
void subset_op_kernel(const float* __restrict__ scores,
                      const float* __restrict__ g,
                      float* __restrict__ out) {
  const int tid = threadIdx.x;
  const int lane = tid & 63;
  const int wave = tid >> 6;
  const long long row0 = (long long)blockIdx.x * RPB;

  __shared__ float red[2][NWAVES];

  // ---- stage row0: st[j] = scores + g (coalesced float4, stride 1024) ----
  f32x4 st[VECS];
  {
    const long long rbase = row0 * NCOLS;
#pragma unroll
    for (int j = 0; j < VECS; ++j) {
      const int off = j * 1024 + tid * 4;
      const f32x4 sv = *(const f32x4*)(scores + rbase + off);
      const f32x4 gv = *(const f32x4*)(g + rbase + off);
      st[j] = sv + gv;
    }
  }

#pragma unroll
  for (int r = 0; r < RPB; ++r) {
    // ---- convert staged logits: w = exp(st - M0); kh = 0; first sum ----
    f32x2 w2[2 * VECS], kh2[2 * VECS];
    f32x2 acc0 = {0.0f, 0.0f}, acc1 = {0.0f, 0.0f};
#pragma unroll
    for (int j = 0; j < VECS; ++j) {
      f32x2 lo, hi;
      lo.x = __expf(st[j].x - M0); lo.y = __expf(st[j].y - M0);
      hi.x = __expf(st[j].z - M0); hi.y = __expf(st[j].w - M0);
      w2[2 * j] = lo;  w2[2 * j + 1] = hi;
      kh2[2 * j] = (f32x2){0.0f, 0.0f};
      kh2[2 * j + 1] = (f32x2){0.0f, 0.0f};
      acc0 += lo; acc1 += hi;
    }
    const f32x2 accv = acc0 + acc1;
    float sum = accv.x + accv.y;

    // ---- prefetch next row into st; K-loop below has no VMEM ops, so the
    //      loads complete for free behind it ----
    if (r + 1 < RPB) {
      const long long rbase = (row0 + r + 1) * NCOLS;
#pragma unroll
      for (int j = 0; j < VECS; ++j) {
        const int off = j * 1024 + tid * 4;
        const f32x4 sv = *(const f32x4*)(scores + rbase + off);
        const f32x4 gv = *(const f32x4*)(g + rbase + off);
        st[j] = sv + gv;
      }
    }

    // ---- K iterations: sum-reduce, packed multiplicative mask update ----
#pragma unroll 1
    for (int k = 0; k < KITER; ++k) {
      float ps = sum;
#pragma unroll
      for (int off = 32; off > 0; off >>= 1) ps += __shfl_xor(ps, off);
      if (lane == 0) red[k & 1][wave] = ps;
      __syncthreads();
      const float tot = (red[k & 1][0] + red[k & 1][1]) +
                        (red[k & 1][2] + red[k & 1][3]);
      const float inv = 1.0f / tot;

      f32x2 s0 = {0.0f, 0.0f}, s1 = {0.0f, 0.0f};
      f32x2 s2 = {0.0f, 0.0f}, s3 = {0.0f, 0.0f};
#pragma unroll
      for (int j = 0; j < 2 * VECS; ++j) {
        const f32x2 oh = w2[j] * inv;                     // onehot pair
        kh2[j] += oh;                                     // khot accumulate
        w2[j] = __builtin_elementwise_fma(-oh, w2[j], w2[j]);  // w *= (1-oh)
        if ((j & 3) == 0)      s0 += w2[j];
        else if ((j & 3) == 1) s1 += w2[j];
        else if ((j & 3) == 2) s2 += w2[j];
        else                   s3 += w2[j];
      }
      const f32x2 sv2 = (s0 + s1) + (s2 + s3);
      sum = sv2.x + sv2.y;
    }

    // ---- store khot for row r (nontemporal) ----
    {
      const long long rbase = (row0 + r) * NCOLS;
#pragma unroll
      for (int j = 0; j < VECS; ++j) {
        const int off = j * 1024 + tid * 4;
        f32x4 v;
        v.x = kh2[2 * j].x;     v.y = kh2[2 * j].y;
        v.z = kh2[2 * j + 1].x; v.w = kh2[2 * j + 1].y;
        __builtin_nontemporal_store(v, (f32x4*)(out + rbase + off));
      }
    }
  }
}

extern "C" void kernel_launch(void* const* d_in, const int* in_sizes, int n_in,
                              void* d_out, int out_size, void* d_ws, size_t ws_size,
                              hipStream_t stream) {
  const float* scores = (const float*)d_in[0];
  const float* g = (const float*)d_in[1];
  float* out = (float*)d_out;
  (void)in_sizes; (void)n_in; (void)out_size; (void)d_ws; (void)ws_size;

  subset_op_kernel<<<GRID, THREADS, 0, stream>>>(scores, g, out);
}